// Round 1
// baseline (31218.704 us; speedup 1.0000x reference)
//
#include <hip/hip_runtime.h>
#include <hip/hip_bf16.h>
#include <stdint.h>

// GRU: B=64, T=512, I=1024, H=1024, fp32 in/out, bf16 MFMA compute.
// Requires ws_size >= ~285 MB (layout documented in kernel_launch).

#define B_ 64
#define T_ 512
#define I_ 1024
#define H_ 1024
#define BT_ (B_*T_)                 // 32768
#define N3_ (3*H_)                  // 3072
#define GATE_STRIDE ((size_t)B_*T_*H_)  // 33554432 elems per gate in xproj

typedef unsigned short u16;
typedef unsigned int u32;
typedef __attribute__((ext_vector_type(8))) short s16x8;   // 8 bf16 in 4 VGPRs (MFMA A/B frag)
typedef __attribute__((ext_vector_type(4))) float f32x4;   // MFMA C/D frag

__device__ __forceinline__ float bf2f(u16 u){
  union { u32 u; float f; } v; v.u = ((u32)u) << 16; return v.f;
}
__device__ __forceinline__ u16 f2bf(float f){
  union { float f; u32 u; } v; v.f = f;
  return (u16)((v.u + 0x7FFFu + ((v.u >> 16) & 1u)) >> 16);
}
__device__ __forceinline__ u32 pack2(float a, float b){
  return (u32)f2bf(a) | ((u32)f2bf(b) << 16);
}

// ---------- f32 -> bf16 conversion, 8 elems/thread ----------
__global__ void cvt_bf16_kernel(const float* __restrict__ s, u16* __restrict__ d, int n8){
  int i = blockIdx.x * blockDim.x + threadIdx.x;
  if (i >= n8) return;
  const float4* s4 = (const float4*)s + (size_t)i * 2;
  float4 v0 = s4[0], v1 = s4[1];
  uint4 o;
  o.x = pack2(v0.x, v0.y); o.y = pack2(v0.z, v0.w);
  o.z = pack2(v1.x, v1.y); o.w = pack2(v1.z, v1.w);
  ((uint4*)d)[i] = o;
}

// ---------- Phase 1: xproj[gate][b][t][h] = (inputs @ W_i^T + biases), bf16 out ----------
// M=32768 (b*512+t), N=3072 (gate*1024+h), K=1024. 128x128 tile, 4 waves (2x2 of 64x64).
// Reg-staged LDS with XOR swizzle -> conflict-free ds_read_b128.
__global__ __launch_bounds__(256) void gemm_xproj(
    const u16* __restrict__ Xbf, const u16* __restrict__ Wi,
    const float* __restrict__ b_ir, const float* __restrict__ b_iz, const float* __restrict__ b_in_,
    const float* __restrict__ b_hr, const float* __restrict__ b_hz,
    u16* __restrict__ xproj)
{
  __shared__ u16 Alds[128*64];   // [row][k] bf16, row stride 128B, swizzled
  __shared__ u16 Blds[128*64];
  const int tid = threadIdx.x;
  const int l = tid & 63, w = tid >> 6;
  const int lr = l & 15, lq = l >> 4;
  const int wm = w >> 1, wn = w & 1;
  const int m0 = blockIdx.x * 128, n0 = blockIdx.y * 128;

  f32x4 acc[4][4];
  #pragma unroll
  for (int m = 0; m < 4; m++){
    #pragma unroll
    for (int n = 0; n < 4; n++) acc[m][n] = (f32x4){0.f, 0.f, 0.f, 0.f};
  }

  // staging: thread covers 16B chunks; chunk c -> row rr+c*32, kbyte (tid&7)*16
  const int rr = tid >> 3;                    // 0..31
  const int kbyte = (tid & 7) * 16;
  const int swz = kbyte ^ ((rr & 7) << 4);    // XOR swizzle (bank-conflict-free reads)
  const u16* Ag = Xbf + (size_t)(m0 + rr) * 1024 + (tid & 7) * 8;
  const u16* Bg = Wi  + (size_t)(n0 + rr) * 1024 + (tid & 7) * 8;

  uint4 a_regs[4], b_regs[4];
  #pragma unroll
  for (int c = 0; c < 4; c++){
    a_regs[c] = *(const uint4*)(Ag + c * 32 * 1024);
    b_regs[c] = *(const uint4*)(Bg + c * 32 * 1024);
  }

  for (int ks = 0; ks < 16; ks++){
    __syncthreads();   // previous tile's reads done
    #pragma unroll
    for (int c = 0; c < 4; c++){
      *(uint4*)((char*)Alds + (rr + c * 32) * 128 + swz) = a_regs[c];
      *(uint4*)((char*)Blds + (rr + c * 32) * 128 + swz) = b_regs[c];
    }
    __syncthreads();
    if (ks < 15){      // prefetch next K-tile (overlaps with MFMA below)
      const u16* Ag2 = Ag + (ks + 1) * 64;
      const u16* Bg2 = Bg + (ks + 1) * 64;
      #pragma unroll
      for (int c = 0; c < 4; c++){
        a_regs[c] = *(const uint4*)(Ag2 + c * 32 * 1024);
        b_regs[c] = *(const uint4*)(Bg2 + c * 32 * 1024);
      }
    }
    #pragma unroll
    for (int kk = 0; kk < 2; kk++){
      s16x8 af[4], bfr[4];
      const int kb = kk * 64 + lq * 16;
      #pragma unroll
      for (int m = 0; m < 4; m++){
        int row = wm * 64 + m * 16 + lr;
        af[m] = *(const s16x8*)((const char*)Alds + row * 128 + (kb ^ ((row & 7) << 4)));
      }
      #pragma unroll
      for (int n = 0; n < 4; n++){
        int row = wn * 64 + n * 16 + lr;
        bfr[n] = *(const s16x8*)((const char*)Blds + row * 128 + (kb ^ ((row & 7) << 4)));
      }
      #pragma unroll
      for (int m = 0; m < 4; m++){
        #pragma unroll
        for (int n = 0; n < 4; n++)
          acc[m][n] = __builtin_amdgcn_mfma_f32_16x16x32_bf16(af[m], bfr[n], acc[m][n], 0, 0, 0);
      }
    }
  }

  // epilogue: C/D layout col=lane&15, row=(lane>>4)*4+j (m89-verified)
  #pragma unroll
  for (int n = 0; n < 4; n++){
    int gn = n0 + wn * 64 + n * 16 + lr;
    int gate = gn >> 10, hh = gn & 1023;
    float bias = (gate == 0) ? (b_ir[hh] + b_hr[hh])
               : (gate == 1) ? (b_iz[hh] + b_hz[hh])
               : b_in_[hh];
    #pragma unroll
    for (int m = 0; m < 4; m++){
      #pragma unroll
      for (int j = 0; j < 4; j++){
        int gm = m0 + wm * 64 + m * 16 + lq * 4 + j;
        int b = gm >> 9, t = gm & 511;
        size_t idx = (size_t)gate * GATE_STRIDE + ((size_t)(b * 512 + t)) * 1024 + hh;
        xproj[idx] = f2bf(acc[m][n][j] + bias);
      }
    }
  }
}

// ---------- Phase 2: sequential scan, persistent kernel ----------
// 256 blocks = 4 batch-groups (16 batches) x 64 col-tiles (16 cols).
// Per step: stage h-tile (bf16) into swizzled LDS; waves 0-2 do gate GEMMs (K=1024,
// 32 MFMA each); wave 3 prefetches xproj tile; epilogue computes gates + h_new.
// Sync: per-group monotonic atomic barrier (64 blocks/group, 4 independent groups).
__global__ __launch_bounds__(256) void gru_scan(
    const u16* __restrict__ Wh, const u16* __restrict__ xproj,
    const float* __restrict__ h0, const float* __restrict__ b_hn,
    float* __restrict__ out, u16* __restrict__ stbuf, u32* __restrict__ bar)
{
  __shared__ u16 Asw[16 * 1024];      // 32 KB swizzled h-tile [16 rows][2048B]
  __shared__ float gbuf[3][16][17];   // gate partials, padded
  __shared__ u16 xls[3 * 256];        // xproj tile for this step

  const int tid = threadIdx.x;
  const int l = tid & 63, w = tid >> 6;
  const int lr = l & 15, lq = l >> 4;
  // XCD-aware mapping: all 4 batch-groups of a col-cluster share an XCD's L2 weights
  const int id = blockIdx.x;
  const int xcd = id & 7, slot = id >> 3;
  const int ct = xcd * 8 + (slot & 7);   // col-tile 0..63
  const int bt = slot >> 3;              // batch-group 0..3

  const int bi = tid >> 4, ci = tid & 15;
  const int b = bt * 16 + bi;
  const int hh = ct * 16 + ci;

  // init: h state lives in a register; bf16 mirror in global for MFMA
  float hprev = h0[b * 1024 + hh];
  stbuf[b * 1024 + hh] = f2bf(hprev);
  __threadfence();
  __syncthreads();
  if (tid == 0){
    u32 arr = __hip_atomic_fetch_add(&bar[bt], 1u, __ATOMIC_ACQ_REL, __HIP_MEMORY_SCOPE_AGENT) + 1;
    if (arr == 64u) __hip_atomic_store(&bar[4 + bt], 1u, __ATOMIC_RELEASE, __HIP_MEMORY_SCOPE_AGENT);
    else while (__hip_atomic_load(&bar[4 + bt], __ATOMIC_ACQUIRE, __HIP_MEMORY_SCOPE_AGENT) < 1u)
      __builtin_amdgcn_s_sleep(2);
  }
  __syncthreads();
  __threadfence();

  const float bhn = b_hn[hh];

  #pragma unroll 1
  for (int t = 0; t < 512; t++){
    const int cur = t & 1;
    const u16* stG = stbuf + cur * 65536 + bt * 16 * 1024;
    // stage h-tile -> swizzled LDS (conflict-free writes and reads)
    #pragma unroll
    for (int c = 0; c < 8; c++){
      int byteoff = c * 4096 + tid * 16;
      int row = byteoff >> 11;
      int kb = byteoff & 2047;
      uint4 v = *(const uint4*)((const char*)stG + byteoff);
      *(uint4*)((char*)Asw + row * 2048 + (kb ^ ((row & 7) << 4))) = v;
    }
    __syncthreads();

    if (w < 3){
      const int g = w;
      const u16* Brow = Wh + (size_t)(g * 1024 + ct * 16 + lr) * 1024 + lq * 8;
      const char* Abase = (const char*)Asw + lr * 2048;
      const int swz_r = (lr & 7) << 4;
      f32x4 acc = (f32x4){0.f, 0.f, 0.f, 0.f};
      #pragma unroll 4
      for (int kk = 0; kk < 32; kk++){
        int kb = kk * 64 + lq * 16;
        s16x8 a  = *(const s16x8*)(Abase + (kb ^ swz_r));
        s16x8 bb = *(const s16x8*)(Brow + kk * 32);
        acc = __builtin_amdgcn_mfma_f32_16x16x32_bf16(a, bb, acc, 0, 0, 0);
      }
      #pragma unroll
      for (int j = 0; j < 4; j++) gbuf[g][lq * 4 + j][lr] = acc[j];
    } else {
      if (l < 48){   // wave 3: prefetch xproj tile (overlaps MFMA)
        int g = l >> 4, bi2 = l & 15;
        const u16* src = xproj + (size_t)g * GATE_STRIDE
                       + ((size_t)((bt * 16 + bi2) * 512 + t)) * 1024 + ct * 16;
        uint4 v0 = *(const uint4*)(src);
        uint4 v1 = *(const uint4*)(src + 8);
        *(uint4*)(&xls[g * 256 + bi2 * 16]) = v0;
        *(uint4*)(&xls[g * 256 + bi2 * 16 + 8]) = v1;
      }
    }
    __syncthreads();

    // epilogue: this thread owns (b, hh)
    float aR = gbuf[0][bi][ci];
    float aZ = gbuf[1][bi][ci];
    float aN = gbuf[2][bi][ci];
    float xr = bf2f(xls[0 * 256 + bi * 16 + ci]);   // includes b_ir + b_hr
    float xz = bf2f(xls[1 * 256 + bi * 16 + ci]);   // includes b_iz + b_hz
    float xn = bf2f(xls[2 * 256 + bi * 16 + ci]);   // includes b_in
    float r = 1.f / (1.f + exp2f(-1.4426950408889634f * (xr + aR)));
    float z = 1.f / (1.f + exp2f(-1.4426950408889634f * (xz + aZ)));
    float narg = xn + r * (aN + bhn);
    float e2 = exp2f(fminf(fmaxf(2.8853900817779268f * narg, -60.f), 60.f));
    float n = (e2 - 1.f) / (e2 + 1.f);
    float hnew = (1.f - z) * n + z * hprev;
    hprev = hnew;
    out[((size_t)(b * 512 + t)) * 1024 + hh] = hnew;
    stbuf[(cur ^ 1) * 65536 + b * 1024 + hh] = f2bf(hnew);

    if (t < 511){
      __threadfence();     // publish h_new (bf16) agent-wide
      __syncthreads();
      if (tid == 0){
        u32 ev = (u32)(t + 2);
        u32 arr = __hip_atomic_fetch_add(&bar[bt], 1u, __ATOMIC_ACQ_REL, __HIP_MEMORY_SCOPE_AGENT) + 1;
        if (arr == ev * 64u) __hip_atomic_store(&bar[4 + bt], ev, __ATOMIC_RELEASE, __HIP_MEMORY_SCOPE_AGENT);
        else while (__hip_atomic_load(&bar[4 + bt], __ATOMIC_ACQUIRE, __HIP_MEMORY_SCOPE_AGENT) < ev)
          __builtin_amdgcn_s_sleep(2);
      }
      __syncthreads();
      __threadfence();     // acquire side: invalidate stale cached h
    }
  }
  // h_last
  out[GATE_STRIDE + (size_t)b * 1024 + hh] = hprev;
}

extern "C" void kernel_launch(void* const* d_in, const int* in_sizes, int n_in,
                              void* d_out, int out_size, void* d_ws, size_t ws_size,
                              hipStream_t stream)
{
  const float* inputs = (const float*)d_in[0];
  const float* hidden = (const float*)d_in[1];
  const float* w_ir = (const float*)d_in[2];
  const float* w_iz = (const float*)d_in[3];
  const float* w_in_ = (const float*)d_in[4];
  const float* b_ir = (const float*)d_in[5];
  const float* b_iz = (const float*)d_in[6];
  const float* b_in_ = (const float*)d_in[7];
  const float* w_hr = (const float*)d_in[8];
  const float* w_hz = (const float*)d_in[9];
  const float* w_hn = (const float*)d_in[10];
  const float* b_hr = (const float*)d_in[11];
  const float* b_hz = (const float*)d_in[12];
  const float* b_hn = (const float*)d_in[13];

  // ws layout (bytes):
  //   [0, 4K)            barrier counters (bar[0..3]=cnt, bar[4..7]=gen)
  //   [4K, 260K)         stbuf: 2 x [64][1024] bf16 h double-buffer
  //   [512K, 6.5M)       Wi bf16 [3072][1024]
  //   [8M, 14M)          Wh bf16 [3072][1024]
  //   [16M, 80M)         Xbf bf16 [32768][1024]
  //   [80M, 272M)        xproj bf16 [3][64][512][1024]
  char* ws = (char*)d_ws;
  u32* bar    = (u32*)(ws + 0);
  u16* stbuf  = (u16*)(ws + 4096);
  u16* Wi     = (u16*)(ws + (1 << 19));
  u16* Wh     = (u16*)(ws + (8 << 20));
  u16* Xbf    = (u16*)(ws + (16 << 20));
  u16* xprojp = (u16*)(ws + (80 << 20));
  float* outp = (float*)d_out;

  hipMemsetAsync(bar, 0, 4096, stream);

  // conversions (8 elems/thread)
  {
    int n8 = BT_ * I_ / 8;   // 4,194,304
    cvt_bf16_kernel<<<(n8 + 255) / 256, 256, 0, stream>>>(inputs, Xbf, n8);
    int w8 = H_ * I_ / 8;    // 131,072
    cvt_bf16_kernel<<<(w8 + 255) / 256, 256, 0, stream>>>(w_ir, Wi, w8);
    cvt_bf16_kernel<<<(w8 + 255) / 256, 256, 0, stream>>>(w_iz, Wi + (size_t)H_ * I_, w8);
    cvt_bf16_kernel<<<(w8 + 255) / 256, 256, 0, stream>>>(w_in_, Wi + (size_t)2 * H_ * I_, w8);
    cvt_bf16_kernel<<<(w8 + 255) / 256, 256, 0, stream>>>(w_hr, Wh, w8);
    cvt_bf16_kernel<<<(w8 + 255) / 256, 256, 0, stream>>>(w_hz, Wh + (size_t)H_ * H_, w8);
    cvt_bf16_kernel<<<(w8 + 255) / 256, 256, 0, stream>>>(w_hn, Wh + (size_t)2 * H_ * H_, w8);
  }

  dim3 g(BT_ / 128, N3_ / 128, 1);   // 256 x 24
  gemm_xproj<<<g, 256, 0, stream>>>(Xbf, Wi, b_ir, b_iz, b_in_, b_hr, b_hz, xprojp);

  gru_scan<<<256, 256, 0, stream>>>(Wh, xprojp, hidden, b_hn, outp, stbuf, bar);
}